// Round 12
// baseline (86.438 us; speedup 1.0000x reference)
//
#include <hip/hip_runtime.h>

// LogicConv3d: B=4, C=3, H=W=D=32, K=32, S=16 leaves, tree depth 4 (31 LUT nodes).
// Out: (B, K, 30, 30, 30) = 3,456,000 fp32.
//
// R11: all-global fp16 gathers, no LDS slab. Pre-pass writes 3 d-shifted fp16
// copies of x into d_ws (y_r[i] = fp16(x[i+r]), 2.4 MB, L2-resident). A leaf
// with d-coord ld reads copy ld, so every 8-od octet gather is ONE 16B-aligned
// dwordx4 (od0 in {0,8,16,24}, all bases multiple of 8 elems). vs R10: gather
// instrs 96 -> 32 per thread, gather bytes halved, no staging/ds_write/syncthreads
// machinery, no od duplication (od0=24 octet stores only od 24..29).
// Eval in fp32 (cvt after load); fp16 input quantization adds ~1e-3 absmax
// (threshold 1.25e-2, previous 1.95e-3).

#define B_  4
#define C_  3
#define H_  32
#define W_  32
#define D_  32
#define K_  32
#define S_  16
#define TPB 256
#define NX  393216   // total x elements (B*C*H*W*D)

typedef float    v8f __attribute__((ext_vector_type(8)));
typedef _Float16 h8  __attribute__((ext_vector_type(8), aligned(16)));
typedef float    f4a __attribute__((ext_vector_type(4), aligned(4)));
typedef float    f2a __attribute__((ext_vector_type(2), aligned(4)));

__device__ __forceinline__ v8f cvt8(h8 h) {
    v8f r;
    #pragma unroll
    for (int i = 0; i < 8; ++i) r[i] = (float)h[i];
    return r;
}

__device__ __forceinline__ v8f lut8(v8f a, v8f b, float l0, float d1, float d2, float d3) {
    // E = l0 + a*d2 + b*d1 + (a*b)*d3 == fma(b, fma(a,d3,d1), fma(a,d2,l0))
    const v8f t0 = a * d2 + l0;
    const v8f t1 = a * d3 + d1;
    return b * t1 + t0;
}

__global__ __launch_bounds__(TPB) void prepass(const float* __restrict__ x,
                                               _Float16* __restrict__ y) {
    const int i = blockIdx.x * TPB + threadIdx.x;   // 0..NX-1
    const int d = i & 31;
    const float v0 = x[i];
    const float v1 = (d < 31) ? x[i + 1] : 0.f;     // shifted copies; tail zeroed
    const float v2 = (d < 30) ? x[i + 2] : 0.f;     // (feeds only dropped od 30/31)
    y[i]          = (_Float16)v0;
    y[NX + i]     = (_Float16)v1;
    y[2 * NX + i] = (_Float16)v2;
}

__global__ __launch_bounds__(TPB, 4) void logic_conv3d(
    const _Float16* __restrict__ y,
    const int*      __restrict__ kc,
    const float*    __restrict__ w0,
    const float*    __restrict__ w1,
    const float*    __restrict__ w2,
    const float*    __restrict__ w3,
    const float*    __restrict__ w4,
    float*          __restrict__ out)
{
    __shared__ float4 s_lut[31];     // (l0, d1, d2, d3) per node
    __shared__ int    s_lb[32];      // leaf base: ld*NX + ((c*32+lh)*32+lw)*32

    const int bk  = blockIdx.x;      // b*K + k
    const int b   = bk >> 5;
    const int k   = bk & 31;
    const int tid = threadIdx.x;

    // ---- per-block setup: 31 softmax->LUT (delta form) + 32 leaf bases ----
    if (tid < 31) {
        const float* wp; int ln;
        if      (tid < 16) { wp = w0; ln = tid;      }
        else if (tid < 24) { wp = w1; ln = tid - 16; }
        else if (tid < 28) { wp = w2; ln = tid - 24; }
        else if (tid < 30) { wp = w3; ln = tid - 28; }
        else               { wp = w4; ln = 0;        }
        const float* wrow = wp + (ln * K_ + k) * 16;
        float lg[16];
        float m = -1e30f;
        #pragma unroll
        for (int g = 0; g < 16; ++g) { lg[g] = wrow[g]; m = fmaxf(m, lg[g]); }
        float z = 0.f;
        #pragma unroll
        for (int g = 0; g < 16; ++g) { lg[g] = __expf(lg[g] - m); z += lg[g]; }
        const float inv = 1.0f / z;
        float l0 = 0.f, l1 = 0.f, l2 = 0.f, l3 = 0.f;
        #pragma unroll
        for (int g = 0; g < 16; ++g) {
            float p = lg[g] * inv;           // GATES[g,t] = (g>>t)&1, t = 2*a+b
            if (g & 1) l0 += p;
            if (g & 2) l1 += p;
            if (g & 4) l2 += p;
            if (g & 8) l3 += p;
        }
        s_lut[tid] = make_float4(l0, l1 - l0, l2 - l0, (l3 - l2) - (l1 - l0));
    } else if (tid >= 32 && tid < 64) {
        const int idx  = tid - 32;           // tree*16 + s
        const int tree = idx >> 4;
        const int s    = idx & 15;
        const int off  = ((tree * K_ + k) * S_ + s) * 4;  // kc (2,K,S,4) = (h,w,d,c)
        const int h = kc[off + 0], w = kc[off + 1], d = kc[off + 2], c = kc[off + 3];
        // copy d, base multiple of 32 elems -> every octet gather 16B-aligned
        s_lb[idx] = d * NX + ((c * H_ + h) * W_ + w) * D_;
    }
    __syncthreads();

    // block-uniform leaf bases -> SGPRs (8 aligned b128 + readfirstlane)
    int sAB[32];
    #pragma unroll
    for (int i = 0; i < 8; ++i) {
        const int4 q = *(const int4*)&s_lb[i * 4];
        sAB[i * 4 + 0] = __builtin_amdgcn_readfirstlane(q.x);
        sAB[i * 4 + 1] = __builtin_amdgcn_readfirstlane(q.y);
        sAB[i * 4 + 2] = __builtin_amdgcn_readfirstlane(q.z);
        sAB[i * 4 + 3] = __builtin_amdgcn_readfirstlane(q.w);
    }

    // thread -> (oh_local, ow, octet of consecutive od)
    const int ohl = tid >> 7;                // 0,1
    const int r   = tid & 127;
    const int ow  = r >> 2;                  // 0..31 (>=30 inactive)
    const int gq  = r & 3;                   // 0..3
    const int od0 = gq << 3;                 // 0,8,16,24 (24-octet: od 30,31 dropped)

    if (ow < 30) {
        const int oh   = blockIdx.y * 2 + ohl;
        const int voff = b * (C_ * H_ * W_ * D_) + oh * (W_ * D_) + ow * D_ + od0;

        // ---- fused levels 0+1: leaf pair -> level-1 node (64-VGPR acc cap) ----
        v8f v1[8];
        #pragma unroll
        for (int j = 0; j < 8; ++j) {
            const int s0 = 2 * j, s1 = 2 * j + 1;
            const v8f A0 = cvt8(*(const h8*)(y + sAB[s0]      + voff));
            const v8f B0 = cvt8(*(const h8*)(y + sAB[16 + s0] + voff));
            const float4 L0 = s_lut[s0];
            const v8f t0 = lut8(A0, B0, L0.x, L0.y, L0.z, L0.w);
            const v8f A1 = cvt8(*(const h8*)(y + sAB[s1]      + voff));
            const v8f B1 = cvt8(*(const h8*)(y + sAB[16 + s1] + voff));
            const float4 L1 = s_lut[s1];
            const v8f t1 = lut8(A1, B1, L1.x, L1.y, L1.z, L1.w);
            const float4 LN = s_lut[16 + j];
            v1[j] = lut8(t0, t1, LN.x, LN.y, LN.z, LN.w);
        }

        // ---- levels 2..4: widths 4,2,1 at node offsets 24,28,30 ----
        #pragma unroll
        for (int j = 0; j < 4; ++j) {
            const float4 L = s_lut[24 + j];
            v1[j] = lut8(v1[2 * j], v1[2 * j + 1], L.x, L.y, L.z, L.w);
        }
        #pragma unroll
        for (int j = 0; j < 2; ++j) {
            const float4 L = s_lut[28 + j];
            v1[j] = lut8(v1[2 * j], v1[2 * j + 1], L.x, L.y, L.z, L.w);
        }
        {
            const float4 L = s_lut[30];
            v1[0] = lut8(v1[0], v1[1], L.x, L.y, L.z, L.w);
        }

        // store: full octet for gq<3; od 24..29 only for gq==3
        float* outp = out + (size_t)bk * 27000 + oh * 900 + ow * 30 + od0;
        f4a lo; lo[0] = v1[0][0]; lo[1] = v1[0][1]; lo[2] = v1[0][2]; lo[3] = v1[0][3];
        *(f4a*)outp = lo;
        if (gq < 3) {
            f4a hi; hi[0] = v1[0][4]; hi[1] = v1[0][5]; hi[2] = v1[0][6]; hi[3] = v1[0][7];
            *(f4a*)(outp + 4) = hi;
        } else {
            f2a hi2; hi2[0] = v1[0][4]; hi2[1] = v1[0][5];
            *(f2a*)(outp + 4) = hi2;
        }
    }
}

extern "C" void kernel_launch(void* const* d_in, const int* in_sizes, int n_in,
                              void* d_out, int out_size, void* d_ws, size_t ws_size,
                              hipStream_t stream) {
    const float* x  = (const float*)d_in[0];
    const int*   kc = (const int*)d_in[1];
    const float* w0 = (const float*)d_in[2];
    const float* w1 = (const float*)d_in[3];
    const float* w2 = (const float*)d_in[4];
    const float* w3 = (const float*)d_in[5];
    const float* w4 = (const float*)d_in[6];
    float* out = (float*)d_out;
    _Float16* y = (_Float16*)d_ws;           // 3*NX halves = 2.36 MB

    prepass<<<NX / TPB, TPB, 0, stream>>>(x, y);
    dim3 grid(B_ * K_, 15);                  // (bk, oh-pair) = 1920 blocks
    logic_conv3d<<<grid, TPB, 0, stream>>>(y, kc, w0, w1, w2, w3, w4, out);
}